// Round 1
// baseline (366.801 us; speedup 1.0000x reference)
//
#include <hip/hip_runtime.h>
#include <math.h>

#define KCH 256
#define NROWS 2048

typedef __attribute__((ext_vector_type(4))) float f32x4;
typedef __attribute__((ext_vector_type(8))) __bf16 bf16x8;
typedef __attribute__((ext_vector_type(4))) __bf16 bf16x4;

// ---------------- global path tables (order matches Python PATHS enumeration) ----
__device__ __constant__ int GP_L[34]  = {0,0,0,0, 1,1,1,1,1,1,1,1,1, 2,2,2,2,2,2,2,2,2,2,2, 3,3,3,3,3,3,3,3,3,3};
__device__ __constant__ int GP_L1[34] = {0,1,2,3, 0,1,1,1,2,2,2,3,3, 0,1,1,1,2,2,2,2,3,3,3, 0,1,1,2,2,2,3,3,3,3};
__device__ __constant__ int GP_L2[34] = {0,1,2,3, 1,0,1,2,1,2,3,2,3, 2,1,2,3,0,1,2,3,1,2,3, 3,2,3,1,2,3,0,1,2,3};

// ---------------- CG coefficient init (Racah formula, double) -------------------
__device__ double dfact(int n) { double r = 1.0; for (int i = 2; i <= n; ++i) r *= (double)i; return r; }

__device__ double cg_coeff(int l1, int m1, int l2, int m2, int l3, int m3) {
  if (m3 != m1 + m2) return 0.0;
  double pref = sqrt((2.0 * l3 + 1.0) * dfact(l3 + l1 - l2) * dfact(l3 - l1 + l2)
                     * dfact(l1 + l2 - l3) / dfact(l1 + l2 + l3 + 1));
  pref *= sqrt(dfact(l3 + m3) * dfact(l3 - m3) * dfact(l1 - m1) * dfact(l1 + m1)
               * dfact(l2 - m2) * dfact(l2 + m2));
  double s = 0.0;
  for (int k = 0; k <= l1 + l2 - l3; ++k) {
    int d0 = k, d1 = l1 + l2 - l3 - k, d2 = l1 - m1 - k, d3 = l2 + m2 - k;
    int d4 = l3 - l2 + m1 + k, d5 = l3 - l1 - m2 + k;
    if (d0 < 0 || d1 < 0 || d2 < 0 || d3 < 0 || d4 < 0 || d5 < 0) continue;
    double den = dfact(d0) * dfact(d1) * dfact(d2) * dfact(d3) * dfact(d4) * dfact(d5);
    s += ((k & 1) ? -1.0 : 1.0) / den;
  }
  return pref * s;
}

__global__ void cg_init(float* __restrict__ cg) {
  int idx = blockIdx.x * 256 + threadIdx.x;
  if (idx >= 34 * 49) return;
  int gp = idx / 49, r = idx % 49;
  int m1i = r / 7, m2i = r % 7;
  int l3 = GP_L[gp], l1 = GP_L1[gp], l2 = GP_L2[gp];
  float v = 0.f;
  if (m1i <= 2 * l1 && m2i <= 2 * l2) {
    int m1 = m1i - l1, m2 = m2i - l2, m3 = m1 + m2;
    if (m3 >= -l3 && m3 <= l3) v = (float)cg_coeff(l1, m1, l2, m2, l3, m3);
  }
  cg[idx] = v;
}

// ---------------- f32 -> bf16 conversions ---------------------------------------
__global__ void cvt_f32_bf16_4(const float* __restrict__ in, __bf16* __restrict__ out, long n4) {
  long i = (long)blockIdx.x * 256 + threadIdx.x;
  if (i >= n4) return;
  float4 v = ((const float4*)in)[i];
  bf16x4 o;
  o[0] = (__bf16)v.x; o[1] = (__bf16)v.y; o[2] = (__bf16)v.z; o[3] = (__bf16)v.w;
  ((bf16x4*)out)[i] = o;
}

// Wt[j][k] = W[k][j], bf16
__global__ void wt_cvt(const float* __restrict__ W, __bf16* __restrict__ Wt) {
  int j = blockIdx.x, k = threadIdx.x;
  Wt[(j << 8) + k] = (__bf16)W[(k << 8) + j];
}

// ---------------- CG tensor product ---------------------------------------------
template <int l1, int l2, int L>
__device__ __forceinline__ void tp_path(const float* __restrict__ F1, const float* __restrict__ F2,
                                        const float* __restrict__ cgt, float* __restrict__ tp) {
  float v1[2 * l1 + 1], v2[2 * l2 + 1];
#pragma unroll
  for (int a = 0; a < 2 * l1 + 1; ++a) v1[a] = F1[(long)a * KCH];
#pragma unroll
  for (int b = 0; b < 2 * l2 + 1; ++b) v2[b] = F2[(long)b * KCH];
#pragma unroll
  for (int a = 0; a < 2 * l1 + 1; ++a) {
#pragma unroll
    for (int b = 0; b < 2 * l2 + 1; ++b) {
      int mi = a + b - l1 - l2 + L;  // constant after unroll -> static indexing
      if (mi >= 0 && mi <= 2 * L)
        tp[mi] = fmaf(cgt[a * 7 + b], v1[a] * v2[b], tp[mi]);
    }
  }
}

#define TP_CASE(P, A, B)                                            \
  case P:                                                           \
    tp_path<A, B, L>(f1s[A] + ((long)n * (2 * A + 1)) * KCH + k,    \
                     f2s[B] + ((long)n * (2 * B + 1)) * KCH + k,    \
                     cgt, tp);                                      \
    break;

template <int L>
__global__ __launch_bounds__(256) void tp_kernel(
    const float* __restrict__ f10, const float* __restrict__ f11,
    const float* __restrict__ f12, const float* __restrict__ f13,
    const float* __restrict__ f20, const float* __restrict__ f21,
    const float* __restrict__ f22, const float* __restrict__ f23,
    const float* __restrict__ cg, __bf16* __restrict__ Abuf, int cin) {
  const int p = blockIdx.x;
  const int n = blockIdx.y;
  const int k = threadIdx.x;
  const float* f1s[4] = {f10, f11, f12, f13};
  const float* f2s[4] = {f20, f21, f22, f23};
  constexpr int GOFF = (L == 0) ? 0 : (L == 1) ? 4 : (L == 2) ? 13 : 24;
  const float* cgt = cg + (GOFF + p) * 49;
  float tp[2 * L + 1] = {};

  if constexpr (L == 0) {
    switch (p) { TP_CASE(0,0,0) TP_CASE(1,1,1) TP_CASE(2,2,2) TP_CASE(3,3,3) default: break; }
  } else if constexpr (L == 1) {
    switch (p) { TP_CASE(0,0,1) TP_CASE(1,1,0) TP_CASE(2,1,1) TP_CASE(3,1,2) TP_CASE(4,2,1)
                 TP_CASE(5,2,2) TP_CASE(6,2,3) TP_CASE(7,3,2) TP_CASE(8,3,3) default: break; }
  } else if constexpr (L == 2) {
    switch (p) { TP_CASE(0,0,2) TP_CASE(1,1,1) TP_CASE(2,1,2) TP_CASE(3,1,3) TP_CASE(4,2,0)
                 TP_CASE(5,2,1) TP_CASE(6,2,2) TP_CASE(7,2,3) TP_CASE(8,3,1) TP_CASE(9,3,2)
                 TP_CASE(10,3,3) default: break; }
  } else {
    switch (p) { TP_CASE(0,0,3) TP_CASE(1,1,2) TP_CASE(2,1,3) TP_CASE(3,2,1) TP_CASE(4,2,2)
                 TP_CASE(5,2,3) TP_CASE(6,3,0) TP_CASE(7,3,1) TP_CASE(8,3,2) TP_CASE(9,3,3)
                 default: break; }
  }

  __bf16* out = Abuf + ((long)n * (2 * L + 1)) * cin + (long)p * KCH + k;
#pragma unroll
  for (int m = 0; m < 2 * L + 1; ++m) out[(long)m * cin] = (__bf16)tp[m];
}

// ---------------- bf16 MFMA GEMM: C[M][Nc] = A[M][Kd] * Bt[Nc][Kd]^T (+resid) ---
__device__ __forceinline__ void gload_lds16(const void* g, void* l) {
  __builtin_amdgcn_global_load_lds((const __attribute__((address_space(1))) void*)g,
                                   (__attribute__((address_space(3))) void*)l, 16, 0, 0);
}

template <bool OUT_BF16, bool RESID>
__global__ __launch_bounds__(256) void gemm_kernel(
    const __bf16* __restrict__ A, const __bf16* __restrict__ Bt, void* __restrict__ Cv,
    const float* __restrict__ resid, int M, int Nc, int Kd) {
  __shared__ __bf16 As[128 * 64];
  __shared__ __bf16 Bs[128 * 64];
  const int tid = threadIdx.x;
  const int nTN = Nc >> 7;
  const int tM = blockIdx.x / nTN, tN = blockIdx.x % nTN;
  const int lane = tid & 63, wave = tid >> 6;
  const int wm = (wave >> 1) << 6, wn = (wave & 1) << 6;
  const int lr = lane & 15, lk = (lane >> 4) << 3;

  f32x4 acc[4][4] = {};

  const __bf16* Ag = A + (long)(tM * 128 + (tid >> 3)) * Kd + ((tid & 7) << 3);
  const __bf16* Bg = Bt + (long)(tN * 128 + (tid >> 3)) * Kd + ((tid & 7) << 3);
  char* AsB = (char*)As;
  char* BsB = (char*)Bs;

  for (int kt = 0; kt < Kd; kt += 64) {
#pragma unroll
    for (int i = 0; i < 4; ++i)
      gload_lds16(Ag + (long)i * 32 * Kd + kt, AsB + i * 4096 + tid * 16);
#pragma unroll
    for (int i = 0; i < 4; ++i)
      gload_lds16(Bg + (long)i * 32 * Kd + kt, BsB + i * 4096 + tid * 16);
    __syncthreads();

#pragma unroll
    for (int kk = 0; kk < 64; kk += 32) {
      bf16x8 af[4], bfr[4];
#pragma unroll
      for (int mi = 0; mi < 4; ++mi)
        af[mi] = *(const bf16x8*)(AsB + ((wm + mi * 16 + lr) << 7) + ((kk + lk) << 1));
#pragma unroll
      for (int ni = 0; ni < 4; ++ni)
        bfr[ni] = *(const bf16x8*)(BsB + ((wn + ni * 16 + lr) << 7) + ((kk + lk) << 1));
#pragma unroll
      for (int mi = 0; mi < 4; ++mi)
#pragma unroll
        for (int ni = 0; ni < 4; ++ni)
          acc[mi][ni] = __builtin_amdgcn_mfma_f32_16x16x32_bf16(af[mi], bfr[ni], acc[mi][ni], 0, 0, 0);
    }
    __syncthreads();
  }

  const long col0 = (long)tN * 128 + wn + lr;
  const long row0 = (long)tM * 128 + wm + ((lane >> 4) << 2);
#pragma unroll
  for (int mi = 0; mi < 4; ++mi) {
#pragma unroll
    for (int j = 0; j < 4; ++j) {
      long r = row0 + mi * 16 + j;
      long base = r * (long)Nc + col0;
#pragma unroll
      for (int ni = 0; ni < 4; ++ni) {
        long idx = base + ni * 16;
        float v = acc[mi][ni][j];
        if (RESID) v += resid[idx];
        if (OUT_BF16) ((__bf16*)Cv)[idx] = (__bf16)v;
        else          ((float*)Cv)[idx] = v;
      }
    }
  }
}

// ---------------- launch ---------------------------------------------------------
extern "C" void kernel_launch(void* const* d_in, const int* in_sizes, int n_in,
                              void* d_out, int out_size, void* d_ws, size_t ws_size,
                              hipStream_t stream) {
  // dict order: f1_l0, f2_l0, U_0, W_0, f1_l1, f2_l1, U_1, W_1, ...
  const float* F1[4], * F2[4], * Uin[4], * Win[4];
  for (int l = 0; l < 4; ++l) {
    F1[l]  = (const float*)d_in[4 * l + 0];
    F2[l]  = (const float*)d_in[4 * l + 1];
    Uin[l] = (const float*)d_in[4 * l + 2];
    Win[l] = (const float*)d_in[4 * l + 3];
  }
  static const int  cin_[4] = {1024, 2304, 2816, 2560};
  static const int  cum_[4] = {0, 1024, 3328, 6144};
  static const long moff_[4] = {0, 524288, 2097152, 4718592};
  static const int  NPl_[4] = {4, 9, 11, 10};
  static const int  Ml_[4] = {2048, 6144, 10240, 14336};

  char* ws = (char*)d_ws;
  float*  cg   = (float*)ws;                       // 34*49*4 = 6664 B
  __bf16* Ubf  = (__bf16*)(ws + 8192);             // 8704*256*2 = 4,456,448 B
  __bf16* Wtbf = (__bf16*)(ws + 8192 + 4456448);   // 4*65536*2 = 524,288 B
  __bf16* UWt  = (__bf16*)(ws + 5242880);          // 256*8704*2 = 4,456,448 B
  __bf16* Abuf = (__bf16*)(ws + 10485760);         // up to 73,400,320 B (reused per l)

  hipLaunchKernelGGL(cg_init, dim3(7), dim3(256), 0, stream, cg);

  for (int l = 0; l < 4; ++l) {
    hipLaunchKernelGGL(cvt_f32_bf16_4, dim3(cin_[l] / 4), dim3(256), 0, stream,
                       Uin[l], Ubf + (long)cum_[l] * 256, (long)cin_[l] * 64);
    hipLaunchKernelGGL(wt_cvt, dim3(256), dim3(256), 0, stream, Win[l], Wtbf + l * 65536);
  }

  // UWt_l[j][c] = sum_k W[k][j] * U[c][k]  (bf16 out, no residual)
  for (int l = 0; l < 4; ++l) {
    hipLaunchKernelGGL((gemm_kernel<true, false>), dim3(2 * (cin_[l] >> 7)), dim3(256), 0, stream,
                       Wtbf + l * 65536, Ubf + (long)cum_[l] * 256,
                       (void*)(UWt + (long)cum_[l] * 256), (const float*)nullptr,
                       256, cin_[l], 256);
  }

  // per l: TP into Abuf, then out_l = f1_l + Abuf * UWt_l^T
  for (int l = 0; l < 4; ++l) {
    dim3 tg(NPl_[l], 2048);
    switch (l) {
      case 0: hipLaunchKernelGGL((tp_kernel<0>), tg, dim3(256), 0, stream,
                F1[0],F1[1],F1[2],F1[3], F2[0],F2[1],F2[2],F2[3], cg, Abuf, cin_[0]); break;
      case 1: hipLaunchKernelGGL((tp_kernel<1>), tg, dim3(256), 0, stream,
                F1[0],F1[1],F1[2],F1[3], F2[0],F2[1],F2[2],F2[3], cg, Abuf, cin_[1]); break;
      case 2: hipLaunchKernelGGL((tp_kernel<2>), tg, dim3(256), 0, stream,
                F1[0],F1[1],F1[2],F1[3], F2[0],F2[1],F2[2],F2[3], cg, Abuf, cin_[2]); break;
      case 3: hipLaunchKernelGGL((tp_kernel<3>), tg, dim3(256), 0, stream,
                F1[0],F1[1],F1[2],F1[3], F2[0],F2[1],F2[2],F2[3], cg, Abuf, cin_[3]); break;
    }
    hipLaunchKernelGGL((gemm_kernel<false, true>), dim3((Ml_[l] >> 7) * 2), dim3(256), 0, stream,
                       Abuf, UWt + (long)cum_[l] * 256,
                       (void*)((float*)d_out + moff_[l]), F1[l],
                       Ml_[l], 256, cin_[l]);
  }
  (void)in_sizes; (void)n_in; (void)out_size; (void)ws_size;
}

// Round 2
// 152.622 us; speedup vs baseline: 2.4033x; 2.4033x over previous
//
#include <hip/hip_runtime.h>
#include <math.h>

typedef __attribute__((ext_vector_type(4))) float f32x4;
typedef __attribute__((ext_vector_type(8))) __bf16 bf16x8;
typedef __attribute__((ext_vector_type(4))) __bf16 bf16x4;

// ---------------- path tables (order matches Python PATHS enumeration) ----------
__device__ __constant__ int GP_L[34]  = {0,0,0,0, 1,1,1,1,1,1,1,1,1, 2,2,2,2,2,2,2,2,2,2,2, 3,3,3,3,3,3,3,3,3,3};
__device__ __constant__ int GP_L1[34] = {0,1,2,3, 0,1,1,1,2,2,2,3,3, 0,1,1,1,2,2,2,2,3,3,3, 0,1,1,2,2,2,3,3,3,3};
__device__ __constant__ int GP_L2[34] = {0,1,2,3, 1,0,1,2,1,2,3,2,3, 2,1,2,3,0,1,2,3,1,2,3, 3,2,3,1,2,3,0,1,2,3};

// ---------------- CG coefficient init (Racah formula, double) -------------------
__device__ double dfact(int n) { double r = 1.0; for (int i = 2; i <= n; ++i) r *= (double)i; return r; }

__device__ double cg_coeff(int l1, int m1, int l2, int m2, int l3, int m3) {
  if (m3 != m1 + m2) return 0.0;
  double pref = sqrt((2.0 * l3 + 1.0) * dfact(l3 + l1 - l2) * dfact(l3 - l1 + l2)
                     * dfact(l1 + l2 - l3) / dfact(l1 + l2 + l3 + 1));
  pref *= sqrt(dfact(l3 + m3) * dfact(l3 - m3) * dfact(l1 - m1) * dfact(l1 + m1)
               * dfact(l2 - m2) * dfact(l2 + m2));
  double s = 0.0;
  for (int k = 0; k <= l1 + l2 - l3; ++k) {
    int d0 = k, d1 = l1 + l2 - l3 - k, d2 = l1 - m1 - k, d3 = l2 + m2 - k;
    int d4 = l3 - l2 + m1 + k, d5 = l3 - l1 - m2 + k;
    if (d0 < 0 || d1 < 0 || d2 < 0 || d3 < 0 || d4 < 0 || d5 < 0) continue;
    double den = dfact(d0) * dfact(d1) * dfact(d2) * dfact(d3) * dfact(d4) * dfact(d5);
    s += ((k & 1) ? -1.0 : 1.0) / den;
  }
  return pref * s;
}

__global__ void cg_init(float* __restrict__ cg) {
  int idx = blockIdx.x * 256 + threadIdx.x;
  if (idx >= 34 * 49) return;
  int gp = idx / 49, r = idx % 49;
  int m1i = r / 7, m2i = r % 7;
  int l3 = GP_L[gp], l1 = GP_L1[gp], l2 = GP_L2[gp];
  float v = 0.f;
  if (m1i <= 2 * l1 && m2i <= 2 * l2) {
    int m1 = m1i - l1, m2 = m2i - l2, m3 = m1 + m2;
    if (m3 >= -l3 && m3 <= l3) v = (float)cg_coeff(l1, m1, l2, m2, l3, m3);
  }
  cg[idx] = v;
}

// ---------------- conversions ---------------------------------------------------
// all U_l -> bf16, concatenated (segment boundaries in float4 units)
__global__ __launch_bounds__(256) void cvt_u_all(
    const float* __restrict__ u0, const float* __restrict__ u1,
    const float* __restrict__ u2, const float* __restrict__ u3,
    __bf16* __restrict__ out) {
  long i = (long)blockIdx.x * 256 + threadIdx.x;  // float4 index; grid sized exactly
  const long b1 = 65536, b2 = 212992, b3 = 393216;
  const float* src; long s;
  if (i < b1)      { src = u0; s = i; }
  else if (i < b2) { src = u1; s = i - b1; }
  else if (i < b3) { src = u2; s = i - b2; }
  else             { src = u3; s = i - b3; }
  float4 v = ((const float4*)src)[s];
  bf16x4 o;
  o[0] = (__bf16)v.x; o[1] = (__bf16)v.y; o[2] = (__bf16)v.z; o[3] = (__bf16)v.w;
  ((bf16x4*)out)[i] = o;
}

// Wt[l][j][k] = W_l[k][j], bf16
__global__ void wt_cvt_all(const float* __restrict__ w0, const float* __restrict__ w1,
                           const float* __restrict__ w2, const float* __restrict__ w3,
                           __bf16* __restrict__ Wt) {
  int b = blockIdx.x;            // l*256 + j
  int l = b >> 8, j = b & 255, k = threadIdx.x;
  const float* W = (l == 0) ? w0 : (l == 1) ? w1 : (l == 2) ? w2 : w3;
  Wt[((long)l << 16) + (j << 8) + k] = (__bf16)W[(k << 8) + j];
}

// ---------------- CG tensor product (one block per n, all paths) ----------------
template <int l1, int l2, int L>
__device__ __forceinline__ void tp_path2(const float* __restrict__ v1, const float* __restrict__ v2,
                                         const float* __restrict__ cgt, float* __restrict__ tp) {
#pragma unroll
  for (int a = 0; a < 2 * l1 + 1; ++a) {
#pragma unroll
    for (int b = 0; b < 2 * l2 + 1; ++b) {
      int mi = a + b - l1 - l2 + L;   // compile-time after unroll
      if (mi >= 0 && mi <= 2 * L)
        tp[mi] = fmaf(cgt[a * 7 + b], v1[a] * v2[b], tp[mi]);
    }
  }
}

#define TPW(LV, DST, CIN, GOFF, P, L1V, L2V)                                    \
  { float tp[2 * (LV) + 1] = {};                                                \
    tp_path2<L1V, L2V, LV>(v1 + CUM[L1V], v2 + CUM[L2V], cg + ((GOFF) + (P)) * 49, tp); \
    __bf16* o = (DST) + (n * (2 * (LV) + 1)) * (CIN) + (P) * 256 + k;           \
    _Pragma("unroll")                                                           \
    for (int m = 0; m < 2 * (LV) + 1; ++m) o[(long)m * (CIN)] = (__bf16)tp[m]; }

template <int LMASK>
__global__ __launch_bounds__(256) void tp_all(
    const float* __restrict__ f10, const float* __restrict__ f11,
    const float* __restrict__ f12, const float* __restrict__ f13,
    const float* __restrict__ f20, const float* __restrict__ f21,
    const float* __restrict__ f22, const float* __restrict__ f23,
    const float* __restrict__ cg,
    __bf16* __restrict__ A0, __bf16* __restrict__ A1,
    __bf16* __restrict__ A2, __bf16* __restrict__ A3) {
  const long n = blockIdx.x;
  const int k = threadIdx.x;
  constexpr int CUM[4] = {0, 1, 4, 9};
  const float* f1s[4] = {f10, f11, f12, f13};
  const float* f2s[4] = {f20, f21, f22, f23};

  float v1[16], v2[16];
#pragma unroll
  for (int l1 = 0; l1 < 4; ++l1) {
    const float* p1 = f1s[l1] + (n * (2 * l1 + 1)) * 256 + k;
    const float* p2 = f2s[l1] + (n * (2 * l1 + 1)) * 256 + k;
#pragma unroll
    for (int a = 0; a < 2 * l1 + 1; ++a) {
      v1[CUM[l1] + a] = p1[(long)a * 256];
      v2[CUM[l1] + a] = p2[(long)a * 256];
    }
  }

  if constexpr (LMASK & 1) {   // L=0, cin=1024, goff=0
    TPW(0, A0, 1024, 0, 0, 0, 0)  TPW(0, A0, 1024, 0, 1, 1, 1)
    TPW(0, A0, 1024, 0, 2, 2, 2)  TPW(0, A0, 1024, 0, 3, 3, 3)
  }
  if constexpr (LMASK & 2) {   // L=1, cin=2304, goff=4
    TPW(1, A1, 2304, 4, 0, 0, 1)  TPW(1, A1, 2304, 4, 1, 1, 0)
    TPW(1, A1, 2304, 4, 2, 1, 1)  TPW(1, A1, 2304, 4, 3, 1, 2)
    TPW(1, A1, 2304, 4, 4, 2, 1)  TPW(1, A1, 2304, 4, 5, 2, 2)
    TPW(1, A1, 2304, 4, 6, 2, 3)  TPW(1, A1, 2304, 4, 7, 3, 2)
    TPW(1, A1, 2304, 4, 8, 3, 3)
  }
  if constexpr (LMASK & 4) {   // L=2, cin=2816, goff=13
    TPW(2, A2, 2816, 13, 0, 0, 2)  TPW(2, A2, 2816, 13, 1, 1, 1)
    TPW(2, A2, 2816, 13, 2, 1, 2)  TPW(2, A2, 2816, 13, 3, 1, 3)
    TPW(2, A2, 2816, 13, 4, 2, 0)  TPW(2, A2, 2816, 13, 5, 2, 1)
    TPW(2, A2, 2816, 13, 6, 2, 2)  TPW(2, A2, 2816, 13, 7, 2, 3)
    TPW(2, A2, 2816, 13, 8, 3, 1)  TPW(2, A2, 2816, 13, 9, 3, 2)
    TPW(2, A2, 2816, 13, 10, 3, 3)
  }
  if constexpr (LMASK & 8) {   // L=3, cin=2560, goff=24
    TPW(3, A3, 2560, 24, 0, 0, 3)  TPW(3, A3, 2560, 24, 1, 1, 2)
    TPW(3, A3, 2560, 24, 2, 1, 3)  TPW(3, A3, 2560, 24, 3, 2, 1)
    TPW(3, A3, 2560, 24, 4, 2, 2)  TPW(3, A3, 2560, 24, 5, 2, 3)
    TPW(3, A3, 2560, 24, 6, 3, 0)  TPW(3, A3, 2560, 24, 7, 3, 1)
    TPW(3, A3, 2560, 24, 8, 3, 2)  TPW(3, A3, 2560, 24, 9, 3, 3)
  }
}

// ---------------- batched bf16 MFMA GEMM with T2 LDS swizzle --------------------
// Per segment s (blocks [start[s], start[s+1])): l = lmap[s];
//   C[M][Nc] = A[M][Kd] * Bt[Nc][Kd]^T (+ resid), row-major.
struct GemmDesc {
  const __bf16* A[4];
  const __bf16* B[4];
  void*         C[4];
  const float*  R[4];
  int start[4];   // segment block-id boundaries (start[0] must be 0)
  int lmap[4];    // segment -> l
  int Kd[4];      // per l
  int Nc[4];      // per l
};

__device__ __forceinline__ void gload_lds16(const void* g, void* l) {
  __builtin_amdgcn_global_load_lds((const __attribute__((address_space(1))) void*)g,
                                   (__attribute__((address_space(3))) void*)l, 16, 0, 0);
}

template <bool OUT_BF16, bool RESID>
__global__ __launch_bounds__(256) void gemm_batched(GemmDesc d) {
  __shared__ __bf16 As[128 * 64];
  __shared__ __bf16 Bs[128 * 64];
  const int tid = threadIdx.x;
  const int bid = blockIdx.x;
  int seg = 0;
  if (bid >= d.start[1]) seg = 1;
  if (bid >= d.start[2]) seg = 2;
  if (bid >= d.start[3]) seg = 3;
  const int l = d.lmap[seg];
  const int rel = bid - d.start[seg];
  const int Kd = d.Kd[l], Nc = d.Nc[l];
  const int nTN = Nc >> 7;
  const int tM = rel / nTN, tN = rel % nTN;

  const int lane = tid & 63, wave = tid >> 6;
  const int wm = (wave >> 1) << 6, wn = (wave & 1) << 6;
  const int lr = lane & 15, lk = (lane >> 4) << 3;

  f32x4 acc[4][4] = {};

  // stage: linear LDS dest (tid*16) + inverse-swizzled global source slot
  const int r32 = tid >> 3;                         // row within 32-row chunk
  const int sl = ((tid & 7) ^ (r32 & 7)) << 3;      // swizzled k-slot (elements)
  const __bf16* Ag = d.A[l] + (long)(tM * 128 + r32) * Kd + sl;
  const __bf16* Bg = d.B[l] + (long)(tN * 128 + r32) * Kd + sl;
  char* AsB = (char*)As;
  char* BsB = (char*)Bs;

  for (int kt = 0; kt < Kd; kt += 64) {
#pragma unroll
    for (int i = 0; i < 4; ++i) {
      gload_lds16(Ag + (long)i * 32 * Kd + kt, AsB + i * 4096 + tid * 16);
      gload_lds16(Bg + (long)i * 32 * Kd + kt, BsB + i * 4096 + tid * 16);
    }
    __syncthreads();

#pragma unroll
    for (int kk = 0; kk < 64; kk += 32) {
      bf16x8 af[4], bfr[4];
#pragma unroll
      for (int mi = 0; mi < 4; ++mi)
        af[mi] = *(const bf16x8*)(AsB + ((wm + mi * 16 + lr) << 7)
                                      + ((((kk + lk) << 1)) ^ ((lr & 7) << 4)));
#pragma unroll
      for (int ni = 0; ni < 4; ++ni)
        bfr[ni] = *(const bf16x8*)(BsB + ((wn + ni * 16 + lr) << 7)
                                       + ((((kk + lk) << 1)) ^ ((lr & 7) << 4)));
#pragma unroll
      for (int mi = 0; mi < 4; ++mi)
#pragma unroll
        for (int ni = 0; ni < 4; ++ni)
          acc[mi][ni] = __builtin_amdgcn_mfma_f32_16x16x32_bf16(af[mi], bfr[ni], acc[mi][ni], 0, 0, 0);
    }
    __syncthreads();
  }

  const long col0 = (long)tN * 128 + wn + lr;
  const long row0 = (long)tM * 128 + wm + ((lane >> 4) << 2);
#pragma unroll
  for (int mi = 0; mi < 4; ++mi) {
#pragma unroll
    for (int j = 0; j < 4; ++j) {
      long r = row0 + mi * 16 + j;
      long base = r * (long)Nc + col0;
#pragma unroll
      for (int ni = 0; ni < 4; ++ni) {
        long idx = base + ni * 16;
        float v = acc[mi][ni][j];
        if constexpr (RESID) v += d.R[l][idx];
        if constexpr (OUT_BF16) ((__bf16*)d.C[l])[idx] = (__bf16)v;
        else                    ((float*)d.C[l])[idx] = v;
      }
    }
  }
}

// ---------------- launch ---------------------------------------------------------
extern "C" void kernel_launch(void* const* d_in, const int* in_sizes, int n_in,
                              void* d_out, int out_size, void* d_ws, size_t ws_size,
                              hipStream_t stream) {
  const float* F1[4], * F2[4], * Uin[4], * Win[4];
  for (int l = 0; l < 4; ++l) {
    F1[l]  = (const float*)d_in[4 * l + 0];
    F2[l]  = (const float*)d_in[4 * l + 1];
    Uin[l] = (const float*)d_in[4 * l + 2];
    Win[l] = (const float*)d_in[4 * l + 3];
  }
  static const int  cin_[4]  = {1024, 2304, 2816, 2560};
  static const int  cum_[4]  = {0, 1024, 3328, 6144};
  static const long moff_[4] = {0, 524288, 2097152, 4718592};
  static const int  Ml_[4]   = {2048, 6144, 10240, 14336};
  static const long asz_[4]  = {4194304L, 28311552L, 57671680L, 73400320L}; // bytes

  char* ws = (char*)d_ws;
  float*  cg   = (float*)ws;                        // 6664 B
  __bf16* Ubf  = (__bf16*)(ws + 8192);              // 4,456,448 B
  __bf16* Wtbf = (__bf16*)(ws + 8192 + 4456448);    // 524,288 B
  __bf16* UWt  = (__bf16*)(ws + 5242880);           // 4,456,448 B
  const long ABASE = 10485760;
  const bool big = ws_size >= (size_t)(ABASE + asz_[0] + asz_[1] + asz_[2] + asz_[3]);

  __bf16* Ab[4];
  if (big) {
    long off = ABASE;
    for (int l = 0; l < 4; ++l) { Ab[l] = (__bf16*)(ws + off); off += asz_[l]; }
  } else {
    for (int l = 0; l < 4; ++l) Ab[l] = (__bf16*)(ws + ABASE);  // reused
  }

  hipLaunchKernelGGL(cg_init, dim3(7), dim3(256), 0, stream, cg);
  hipLaunchKernelGGL(cvt_u_all, dim3(2176), dim3(256), 0, stream,
                     Uin[0], Uin[1], Uin[2], Uin[3], Ubf);
  hipLaunchKernelGGL(wt_cvt_all, dim3(1024), dim3(256), 0, stream,
                     Win[0], Win[1], Win[2], Win[3], Wtbf);

  // UW GEMMs: UWt_l[j][c] = sum_k W_l[k][j] * U_l[c][k]; one batched launch.
  {
    GemmDesc d;
    int starts[4] = {0, 40, 84, 120};  // order l3,l2,l1,l0 (sizes 40,44,36,16)
    int lmap[4]   = {3, 2, 1, 0};
    for (int s = 0; s < 4; ++s) { d.start[s] = starts[s]; d.lmap[s] = lmap[s]; }
    for (int l = 0; l < 4; ++l) {
      d.A[l] = Wtbf + (long)l * 65536;
      d.B[l] = Ubf + (long)cum_[l] * 256;
      d.C[l] = (void*)(UWt + (long)cum_[l] * 256);
      d.R[l] = nullptr;
      d.Kd[l] = 256;
      d.Nc[l] = cin_[l];
    }
    hipLaunchKernelGGL((gemm_batched<true, false>), dim3(136), dim3(256), 0, stream, d);
  }

  if (big) {
    hipLaunchKernelGGL((tp_all<15>), dim3(2048), dim3(256), 0, stream,
                       F1[0], F1[1], F1[2], F1[3], F2[0], F2[1], F2[2], F2[3],
                       cg, Ab[0], Ab[1], Ab[2], Ab[3]);
    GemmDesc d;
    int starts[4] = {0, 224, 384, 480};  // l3 (224), l2 (160), l1 (96), l0 (32)
    int lmap[4]   = {3, 2, 1, 0};
    for (int s = 0; s < 4; ++s) { d.start[s] = starts[s]; d.lmap[s] = lmap[s]; }
    for (int l = 0; l < 4; ++l) {
      d.A[l] = Ab[l];
      d.B[l] = UWt + (long)cum_[l] * 256;
      d.C[l] = (void*)((float*)d_out + moff_[l]);
      d.R[l] = F1[l];
      d.Kd[l] = cin_[l];
      d.Nc[l] = 256;
    }
    hipLaunchKernelGGL((gemm_batched<false, true>), dim3(512), dim3(256), 0, stream, d);
  } else {
    for (int l = 0; l < 4; ++l) {
      switch (l) {
        case 0: hipLaunchKernelGGL((tp_all<1>), dim3(2048), dim3(256), 0, stream,
                  F1[0],F1[1],F1[2],F1[3], F2[0],F2[1],F2[2],F2[3], cg,
                  Ab[0],Ab[1],Ab[2],Ab[3]); break;
        case 1: hipLaunchKernelGGL((tp_all<2>), dim3(2048), dim3(256), 0, stream,
                  F1[0],F1[1],F1[2],F1[3], F2[0],F2[1],F2[2],F2[3], cg,
                  Ab[0],Ab[1],Ab[2],Ab[3]); break;
        case 2: hipLaunchKernelGGL((tp_all<4>), dim3(2048), dim3(256), 0, stream,
                  F1[0],F1[1],F1[2],F1[3], F2[0],F2[1],F2[2],F2[3], cg,
                  Ab[0],Ab[1],Ab[2],Ab[3]); break;
        case 3: hipLaunchKernelGGL((tp_all<8>), dim3(2048), dim3(256), 0, stream,
                  F1[0],F1[1],F1[2],F1[3], F2[0],F2[1],F2[2],F2[3], cg,
                  Ab[0],Ab[1],Ab[2],Ab[3]); break;
      }
      GemmDesc d;
      for (int s = 0; s < 4; ++s) {
        d.start[s] = (s == 0) ? 0 : 0x7fffffff;
        d.lmap[s] = l;
      }
      for (int ll = 0; ll < 4; ++ll) {
        d.A[ll] = Ab[l];
        d.B[ll] = UWt + (long)cum_[l] * 256;
        d.C[ll] = (void*)((float*)d_out + moff_[l]);
        d.R[ll] = F1[l];
        d.Kd[ll] = cin_[l];
        d.Nc[ll] = 256;
      }
      hipLaunchKernelGGL((gemm_batched<false, true>), dim3((Ml_[l] >> 7) * 2), dim3(256),
                         0, stream, d);
    }
  }
  (void)in_sizes; (void)n_in; (void)out_size; (void)ws_size;
}